// Round 9
// baseline (2790.352 us; speedup 1.0000x reference)
//
#include <hip/hip_runtime.h>
#include <hip/hip_bf16.h>

#define K_ITERS 20
#define F_IN 512
#define F_HID 128
#define F_OUT 40
#define PWAVES 8192

// Dataset is FP32 end-to-end (established round 3/6). Output buffer fp32 (16 MB).
// R11 changes (resubmitted R15; four GPU-acquisition timeouts; source identical):
//  - k_prop: DECISIVE MISS-PATH EXPERIMENT. 6 edges per gather instruction
//    (lane l = float4 quad l%10 of edge l/10; 60 active lanes). Meta packed
//    as int2 (src, norm-bits), one per-lane load per 6-edge chunk. Self-loop
//    folded into CSR (norm = dinv^2). Rows padded to x6. 4-block segmentation
//    reverted (R4 null). Per-node reduction of the 6 partial float4 sets via
//    wave-private LDS (no barriers). If ~18cyc/gather is per-instruction ->
//    3-4x on k_prop; if per-line -> null and next lever is row-byte shrink.
//  - k_mlp: x staged through LDS via full-wave coalesced global_load_lds
//    (1KB/instr, was 16B/instr uniform L1-missing loads = ~450K cyc/CU).
//    Reads become 2-distinct-addr b128 (2-way = free). Rest identical to R2.

typedef const float __attribute__((address_space(1)))* glb_fp;
typedef float __attribute__((address_space(3)))* lds_fp;

// ---------- in-degree histogram over col (targets) ----------
__global__ void k_hist(const int* __restrict__ col, int E, int* __restrict__ cnt){
  int e = blockIdx.x*blockDim.x + threadIdx.x;
  if (e < E) atomicAdd(&cnt[col[e]], 1);
}

// ---------- dinv = rsqrt(in_deg + 1) ----------
__global__ void k_dinv(const int* __restrict__ cnt, int N, float* __restrict__ dinv){
  int i = blockIdx.x*blockDim.x + threadIdx.x;
  if (i < N) dinv[i] = rsqrtf((float)(cnt[i] + 1));
}

// ---------- scans over padded counts: pad6(cnt[i]+1 self) ----------
__device__ __forceinline__ int pad6(int c){ return ((c + 5)/6)*6; }

__global__ void k_scan1(const int* __restrict__ cnt, int N, int* __restrict__ bsum){
  __shared__ int sd[256];
  int base = blockIdx.x*2048 + threadIdx.x*8;
  int t = threadIdx.x;
  int s = 0;
  #pragma unroll
  for (int j=0;j<8;++j){ int i=base+j; if (i<N) s += pad6(cnt[i]+1); }
  sd[t] = s; __syncthreads();
  for (int off=1; off<256; off<<=1){
    int v = (t>=off)? sd[t-off] : 0;
    __syncthreads();
    sd[t] += v;
    __syncthreads();
  }
  if (t==255) bsum[blockIdx.x] = sd[255];
}
__global__ void k_scan2(const int* __restrict__ bsum, int NB, int* __restrict__ boff,
                        int* __restrict__ rp, int N){
  __shared__ int sd[256];
  int t = threadIdx.x;
  int v = (t < NB) ? bsum[t] : 0;
  sd[t] = v; __syncthreads();
  for (int off=1; off<256; off<<=1){
    int u = (t>=off)? sd[t-off] : 0;
    __syncthreads();
    sd[t] += u;
    __syncthreads();
  }
  if (t < NB) boff[t] = sd[t] - v;
  if (t == NB-1) rp[N] = sd[t];
}
__global__ void k_scan3(const int* __restrict__ cnt, int N, const int* __restrict__ boff,
                        int* __restrict__ rp){
  __shared__ int sd[256];
  int base = blockIdx.x*2048 + threadIdx.x*8;
  int t = threadIdx.x;
  int c[8]; int s = 0;
  #pragma unroll
  for (int j=0;j<8;++j){ int i=base+j; c[j] = (i<N)? pad6(cnt[i]+1) : 0; s += c[j]; }
  sd[t] = s; __syncthreads();
  for (int off=1; off<256; off<<=1){
    int v = (t>=off)? sd[t-off] : 0;
    __syncthreads();
    sd[t] += v;
    __syncthreads();
  }
  int run = sd[t] - s + boff[blockIdx.x];
  #pragma unroll
  for (int j=0;j<8;++j){ int i=base+j; if (i<N) rp[i] = run; run += c[j]; }
}

// ---------- scatter edges into padded CSR of (src, norm) pairs ----------
__global__ void k_scatter(const int* __restrict__ row, const int* __restrict__ col, int E,
                          const int* __restrict__ rp, int* __restrict__ cur,
                          const float* __restrict__ dinv, int2* __restrict__ pair){
  int e = blockIdx.x*blockDim.x + threadIdx.x;
  if (e >= E) return;
  int r = row[e], c = col[e];
  int p = rp[c] + atomicAdd(&cur[c], 1);
  pair[p] = make_int2(r, __float_as_int(dinv[r]*dinv[c]));
}
// ---------- self-loop entries (norm = dinv^2) ----------
__global__ void k_selfpair(int N, const int* __restrict__ rp, int* __restrict__ cur,
                           const float* __restrict__ dinv, int2* __restrict__ pair){
  int n = blockIdx.x*blockDim.x + threadIdx.x;
  if (n >= N) return;
  int p = rp[n] + atomicAdd(&cur[n], 1);
  float di = dinv[n];
  pair[p] = make_int2(n, __float_as_int(di*di));
}

// ---------- fused MLP: x AND W1 staged via coalesced global_load_lds ----------
// 256 threads, 64 nodes/block. GEMM1: th=t&31 owns hids th*4..+3, tn=t>>5 owns
// nodes tn*8..+7. LDS: W dbuf 2x16KB (words 0..8191) + x dbuf 2x8KB (words
// 8192..12287); h1tT[128][68] unions over it after GEMM1.
__global__ __launch_bounds__(256) void k_mlp(const float* __restrict__ x,
                      const float* __restrict__ W1, const float* __restrict__ b1,
                      const float* __restrict__ W2, const float* __restrict__ b2,
                      float* __restrict__ h0, int N){
  __shared__ float lds[12288];       // 48KB
  const int t    = threadIdx.x;
  const int th   = t & 31;
  const int tn   = t >> 5;
  const int lane = t & 63;
  const int wv   = __builtin_amdgcn_readfirstlane(t >> 6);   // 0..3
  const int nb   = blockIdx.x * 64;

  // stage W1 k-tile kt (32 rows x 128 = 16KB contiguous) into buffer b
  auto stage_w = [&](int kt, int b){
    const float* gs = W1 + kt*(32*128) + wv*1024 + lane*4;
    int lo = __builtin_amdgcn_readfirstlane((b*4096 + wv*1024) * 4); // bytes
    #pragma unroll
    for (int i=0;i<4;++i){
      __builtin_amdgcn_global_load_lds((glb_fp)(gs + i*256),
        (lds_fp)((char*)lds + lo + i*1024), 16, 0, 0);
    }
  };
  // stage x tile (64 nodes x 32 k = 8KB, n-major [64][32]) into buffer b
  auto stage_x = [&](int kt, int b){
    #pragma unroll
    for (int s=0;s<2;++s){
      int i = wv*2 + s;                 // 0..7
      int flat = i*256 + lane*4;        // float index in [64][32]
      int n = flat >> 5;
      int kk = flat & 31;
      int node = nb + n; if (node >= N) node = N-1;
      const float* gs = x + (size_t)node*F_IN + kt*32 + kk;
      int lo = __builtin_amdgcn_readfirstlane(32768 + b*8192 + i*1024); // bytes
      __builtin_amdgcn_global_load_lds((glb_fp)gs,
        (lds_fp)((char*)lds + lo), 16, 0, 0);
    }
  };

  float acc[8][4];
  {
    float4 bb = *(const float4*)(b1 + th*4);
    #pragma unroll
    for (int j=0;j<8;++j){ acc[j][0]=bb.x; acc[j][1]=bb.y; acc[j][2]=bb.z; acc[j][3]=bb.w; }
  }

  stage_w(0, 0); stage_x(0, 0);
  __syncthreads();

  for (int kt=0; kt<16; ++kt){
    const int cur = kt & 1;
    if (kt < 15){ stage_w(kt+1, cur^1); stage_x(kt+1, cur^1); }
    const float* xb = lds + 8192 + cur*2048;   // [64][32]
    const float* wb = lds + cur*4096;          // [32][128]
    #pragma unroll
    for (int c=0;c<8;++c){
      float4 xv[8];
      #pragma unroll
      for (int j=0;j<8;++j) xv[j] = *(const float4*)(xb + (tn*8+j)*32 + c*4);
      const float* wl = wb + c*512 + th*4;
      float4 wa = *(const float4*)(wl);
      float4 wb4 = *(const float4*)(wl + 128);
      float4 wc = *(const float4*)(wl + 256);
      float4 wd = *(const float4*)(wl + 384);
      #pragma unroll
      for (int j=0;j<8;++j){
        acc[j][0] += xv[j].x*wa.x; acc[j][1] += xv[j].x*wa.y; acc[j][2] += xv[j].x*wa.z; acc[j][3] += xv[j].x*wa.w;
        acc[j][0] += xv[j].y*wb4.x; acc[j][1] += xv[j].y*wb4.y; acc[j][2] += xv[j].y*wb4.z; acc[j][3] += xv[j].y*wb4.w;
        acc[j][0] += xv[j].z*wc.x; acc[j][1] += xv[j].z*wc.y; acc[j][2] += xv[j].z*wc.z; acc[j][3] += xv[j].z*wc.w;
        acc[j][0] += xv[j].w*wd.x; acc[j][1] += xv[j].w*wd.y; acc[j][2] += xv[j].w*wd.z; acc[j][3] += xv[j].w*wd.w;
      }
    }
    __syncthreads();
  }

  // relu + write h1 transposed: h1tT[hid][node], pad 68 (conflict-free reads)
  #pragma unroll
  for (int h=0; h<4; ++h){
    const int hid = th*4 + h;
    float4 v0 = make_float4(fmaxf(acc[0][h],0.f), fmaxf(acc[1][h],0.f),
                            fmaxf(acc[2][h],0.f), fmaxf(acc[3][h],0.f));
    float4 v1 = make_float4(fmaxf(acc[4][h],0.f), fmaxf(acc[5][h],0.f),
                            fmaxf(acc[6][h],0.f), fmaxf(acc[7][h],0.f));
    *(float4*)&lds[hid*68 + tn*8]     = v0;
    *(float4*)&lds[hid*68 + tn*8 + 4] = v1;
  }
  __syncthreads();

  // GEMM2: wave wv owns cols wv*10..+9; lane = node. W2/b2 via uniform s_load.
  const int c0 = wv*10;
  float a2[10];
  #pragma unroll
  for (int i=0;i<10;++i) a2[i] = b2[c0+i];
  #pragma unroll 4
  for (int k=0;k<F_HID;++k){
    const float hv = lds[k*68 + lane];
    #pragma unroll
    for (int i=0;i<10;++i) a2[i] += hv * W2[k*F_OUT + c0 + i];
  }
  const int gn = nb + lane;
  if (gn < N){
    float* o = h0 + (size_t)gn*F_OUT + c0;
    #pragma unroll
    for (int i=0;i<10;++i) o[i] = fmaxf(a2[i], 0.f);
  }
}

// ---------- propagation: z' = 0.9*(A_hat z) + 0.1*h0 ----------
// Persistent: 8192 waves x ~13 nodes. Per 6-edge chunk: ONE int2 meta load
// (lane -> edge e=l/10) + ONE float4 gather (lane -> quad l%10 of edge e).
// 6 partial float4 accumulator sets, reduced per node via wave-private LDS.
__global__ __launch_bounds__(256, 8) void k_prop(const int* __restrict__ rp,
                      const int2* __restrict__ pair, const float* __restrict__ zin,
                      const float* __restrict__ h0, float* __restrict__ zout,
                      int N, int npw){
  __shared__ float red[4][6][40];
  const int wv   = __builtin_amdgcn_readfirstlane((int)(threadIdx.x >> 6));
  const int W    = blockIdx.x*4 + wv;
  const int lane = threadIdx.x & 63;
  int e_lane = lane/10; if (e_lane > 5) e_lane = 5;
  int qd = lane - e_lane*10; if (qd > 9) qd = 9;      // lanes 60-63 duplicate lane 59
  const int qoff = qd*4;

  for (int k=0; k<npw; ++k){
    const int n = W + k*PWAVES;
    if (n >= N) break;
    const int beg = rp[n];
    const int nch = (rp[n+1] - beg)/6;   // rows padded to x6, >=1 (self)

    float ax=0.f, ay=0.f, az=0.f, aw=0.f;
    const int2* mp = pair + beg + e_lane;

    int2 mA = mp[0];
    float4 zA = *(const float4*)(zin + (size_t)mA.x*F_OUT + qoff);
    int c = 0;
    while (true){
      int2 mB; float4 zB;
      const bool hb = (c+1 < nch);
      if (hb){
        mB = mp[(c+1)*6];
        zB = *(const float4*)(zin + (size_t)mB.x*F_OUT + qoff);
      }
      const float nm = __int_as_float(mA.y);
      ax += nm*zA.x; ay += nm*zA.y; az += nm*zA.z; aw += nm*zA.w;
      if (++c >= nch) break;
      mA = mB; zA = zB;
    }

    if (lane < 60) *(float4*)&red[wv][e_lane][qoff] = make_float4(ax,ay,az,aw);
    if (lane < F_OUT){
      float s = red[wv][0][lane] + red[wv][1][lane] + red[wv][2][lane]
              + red[wv][3][lane] + red[wv][4][lane] + red[wv][5][lane];
      const size_t idx = (size_t)n*F_OUT + lane;
      zout[idx] = 0.9f*s + 0.1f*h0[idx];
    }
  }
}

extern "C" void kernel_launch(void* const* d_in, const int* in_sizes, int n_in,
                              void* d_out, int out_size, void* d_ws, size_t ws_size,
                              hipStream_t stream){
  const float* x  = (const float*)d_in[0];
  const int*   ei = (const int*)d_in[1];
  const float* W1 = (const float*)d_in[2];
  const float* b1 = (const float*)d_in[3];
  const float* W2 = (const float*)d_in[4];
  const float* b2 = (const float*)d_in[5];
  int N = in_sizes[0] / F_IN;
  int E = in_sizes[1] / 2;
  const int* row = ei;       // sources
  const int* col = ei + E;   // targets
  size_t EP = (size_t)E + 7ull*(size_t)N;   // edges + self + pad-to-6 worst case

  char* w = (char*)d_ws;
  auto alloc = [&](size_t bytes)->void*{ void* p = w; w += (bytes + 255) & ~255ull; return p; };
  int*   cnt      = (int*)  alloc((size_t)N*4);
  int*   cur      = (int*)  alloc((size_t)N*4);
  int*   rp       = (int*)  alloc(((size_t)N+1)*4);
  float* dinv     = (float*)alloc((size_t)N*4);
  int NB = (N + 2047)/2048;                 // 49 for N=100000 (<=256)
  int*   bsum     = (int*)  alloc((size_t)NB*4);
  int*   boff     = (int*)  alloc((size_t)NB*4);
  int2*  pair     = (int2*) alloc(EP*8);
  float* h0       = (float*)alloc((size_t)N*F_OUT*4);
  float* zA       = (float*)alloc((size_t)N*F_OUT*4);
  float* zB       = (float*)alloc((size_t)N*F_OUT*4);

  (void)hipMemsetAsync(cnt, 0, (size_t)N*4, stream);
  (void)hipMemsetAsync(cur, 0, (size_t)N*4, stream);
  (void)hipMemsetAsync(pair, 0, EP*8, stream);   // dummy: src=0, norm=0.0f

  int ge = (E + 255)/256;
  k_hist    <<<ge, 256, 0, stream>>>(col, E, cnt);
  k_dinv    <<<(N+255)/256, 256, 0, stream>>>(cnt, N, dinv);
  k_scan1   <<<NB, 256, 0, stream>>>(cnt, N, bsum);
  k_scan2   <<<1, 256, 0, stream>>>(bsum, NB, boff, rp, N);
  k_scan3   <<<NB, 256, 0, stream>>>(cnt, N, boff, rp);
  k_scatter <<<ge, 256, 0, stream>>>(row, col, E, rp, cur, dinv, pair);
  k_selfpair<<<(N+255)/256, 256, 0, stream>>>(N, rp, cur, dinv, pair);

  k_mlp<<<(N+63)/64, 256, 0, stream>>>(x, W1, b1, W2, b2, h0, N);

  int npw = (N + PWAVES - 1)/PWAVES;        // 13 for N=100000
  float* zi = h0; float* zo = zA;
  for (int it=0; it<K_ITERS; ++it){
    float* dst = (it == K_ITERS-1) ? (float*)d_out : zo;   // final iter writes output
    k_prop<<<PWAVES/4, 256, 0, stream>>>(rp, pair, zi, h0, dst, N, npw);
    float* nxt = (it==0) ? zB : zi;
    zi = zo; zo = nxt;
  }
}